// Round 1
// 697.955 us; speedup vs baseline: 1.1615x; 1.1615x over previous
//
#include <hip/hip_runtime.h>
#include <cmath>

constexpr int BB = 8, TT = 96, EE = 96, CC = 256, HHD = 8, DDm = 32;
constexpr int NTOK = BB * TT * EE;   // 73728
constexpr int TOUT = TT / 2;         // 48

typedef unsigned short u16;
typedef short bf16x8 __attribute__((ext_vector_type(8)));
typedef float f32x4 __attribute__((ext_vector_type(4)));

__device__ __forceinline__ float bf2f(u16 u) {
  union { unsigned int i; float f; } v; v.i = ((unsigned int)u) << 16; return v.f;
}
__device__ __forceinline__ u16 f2bf(float f) {
  union { unsigned int i; float f; } v; v.f = f;
  return (u16)((v.i + 0x7FFFu + ((v.i >> 16) & 1u)) >> 16);  // RNE
}
__device__ __forceinline__ float wsum(float v) {
#pragma unroll
  for (int off = 32; off; off >>= 1) v += __shfl_xor(v, off);
  return v;
}
__device__ __forceinline__ float gelu_f(float x) {
  return 0.5f * x * (1.0f + erff(x * 0.70710678118654752f));
}
// token-order permutations: 0=id, 1=[b,t,e]->[b,e,t] position, 2=[b,e,t]->[b,t,e]
__device__ __forceinline__ int remap_row(int row, int mode) {
  if (mode == 0) return row;
  int b = row / (TT * EE);
  int rem = row - b * (TT * EE);
  if (mode == 1) { int t = rem / EE, e = rem - t * EE; return (b * EE + e) * TT + t; }
  int e = rem / TT, t = rem - e * TT;
  return (b * TT + t) * EE + e;
}

// -------- batched weight transpose+convert: 8 x [256,256] fp32 -> bf16 [Nc][K] --------
struct WPtr8 { const float* p[8]; };
__global__ void k_transpose8(WPtr8 src, u16* __restrict__ dst) {
  const float* in = src.p[blockIdx.y];
  u16* out = dst + (size_t)blockIdx.y * 65536;
  int idx = blockIdx.x * 256 + threadIdx.x;
  int k = idx >> 8, c = idx & 255;
  out[c * 256 + k] = f2bf(in[idx]);
}

// -------- weight transpose+convert: W fp32 [K][Nc] -> Wt bf16 [Nc][K] --------
__global__ void k_transpose(const float* __restrict__ in, u16* __restrict__ out, int K, int Nc, int n) {
  int idx = blockIdx.x * 256 + threadIdx.x;
  if (idx < n) {
    int k = idx / Nc, c = idx - k * Nc;
    out[c * K + k] = f2bf(in[idx]);
  }
}

// -------- fp32 -> bf16 convert (adj) --------
__global__ void k_cvt(const float* __restrict__ in, u16* __restrict__ out, int n) {
  int idx = blockIdx.x * 256 + threadIdx.x;
  if (idx < n) out[idx] = f2bf(in[idx]);
}

// ------- LN of fp32 input x -> A = LN(x)*g+b (bf16); no X copy -------
__global__ __launch_bounds__(256) void k_ln_in(const float* __restrict__ x,
                                               u16* __restrict__ A, const float* __restrict__ g,
                                               const float* __restrict__ b) {
  int wv = threadIdx.x >> 6, lane = threadIdx.x & 63;
  long tok = (long)blockIdx.x * 4 + wv;
  int c = lane * 4;
  long off = tok * CC + c;
  float4 v = *(const float4*)(x + off);
  float s = v.x + v.y + v.z + v.w;
  float sq = v.x * v.x + v.y * v.y + v.z * v.z + v.w * v.w;
  s = wsum(s); sq = wsum(sq);
  float m = s * (1.0f / CC);
  float rs = rsqrtf(sq * (1.0f / CC) - m * m + 1e-5f);
  float4 gv = *(const float4*)(g + c);
  float4 bv = *(const float4*)(b + c);
  ushort4 o;
  o.x = f2bf((v.x - m) * rs * gv.x + bv.x);
  o.y = f2bf((v.y - m) * rs * gv.y + bv.y);
  o.z = f2bf((v.z - m) * rs * gv.z + bv.z);
  o.w = f2bf((v.w - m) * rs * gv.w + bv.w);
  *(ushort4*)(A + off) = o;
}

// ---------------- A = LN(X fp32)*g+b ----------------
__global__ __launch_bounds__(256) void k_ln_f32(const float* __restrict__ X, u16* __restrict__ A,
                                                const float* __restrict__ g, const float* __restrict__ b) {
  int wv = threadIdx.x >> 6, lane = threadIdx.x & 63;
  long tok = (long)blockIdx.x * 4 + wv;
  int c = lane * 4;
  long off = tok * CC + c;
  float4 v = *(const float4*)(X + off);
  float s = v.x + v.y + v.z + v.w;
  float sq = v.x * v.x + v.y * v.y + v.z * v.z + v.w * v.w;
  s = wsum(s); sq = wsum(sq);
  float m = s * (1.0f / CC);
  float rs = rsqrtf(sq * (1.0f / CC) - m * m + 1e-5f);
  float4 gv = *(const float4*)(g + c);
  float4 bv = *(const float4*)(b + c);
  ushort4 o;
  o.x = f2bf((v.x - m) * rs * gv.x + bv.x);
  o.y = f2bf((v.y - m) * rs * gv.y + bv.y);
  o.z = f2bf((v.z - m) * rs * gv.z + bv.z);
  o.w = f2bf((v.w - m) * rs * gv.w + bv.w);
  *(ushort4*)(A + off) = o;
}

// ------- spatial combine: reads pristine x; xs = LN1(x); o = LN(P)*s_ng+s_nb;
//         X = x + xs + s_gamma*o (first write of X); A = LN2(X) -------
__global__ __launch_bounds__(256) void k_sp_combine(const float* __restrict__ xin, float* __restrict__ X,
                                                    u16* __restrict__ A, const u16* __restrict__ P,
                                                    const float* __restrict__ n1g, const float* __restrict__ n1b,
                                                    const float* __restrict__ sg,
                                                    const float* __restrict__ s_ng, const float* __restrict__ s_nb,
                                                    const float* __restrict__ n2g, const float* __restrict__ n2b) {
  int wv = threadIdx.x >> 6, lane = threadIdx.x & 63;
  long tok = (long)blockIdx.x * 4 + wv;
  int c = lane * 4;
  long off = tok * CC + c;
  float4 xv = *(const float4*)(xin + off);
  float s1 = xv.x + xv.y + xv.z + xv.w;
  float q1 = xv.x * xv.x + xv.y * xv.y + xv.z * xv.z + xv.w * xv.w;
  s1 = wsum(s1); q1 = wsum(q1);
  float m1 = s1 * (1.0f / CC);
  float r1 = rsqrtf(q1 * (1.0f / CC) - m1 * m1 + 1e-5f);
  float4 g1 = *(const float4*)(n1g + c);
  float4 b1 = *(const float4*)(n1b + c);
  float xs0 = (xv.x - m1) * r1 * g1.x + b1.x;
  float xs1 = (xv.y - m1) * r1 * g1.y + b1.y;
  float xs2 = (xv.z - m1) * r1 * g1.z + b1.z;
  float xs3 = (xv.w - m1) * r1 * g1.w + b1.w;
  ushort4 up = *(const ushort4*)(P + off);
  float4 p = make_float4(bf2f(up.x), bf2f(up.y), bf2f(up.z), bf2f(up.w));
  float s = p.x + p.y + p.z + p.w;
  float sq = p.x * p.x + p.y * p.y + p.z * p.z + p.w * p.w;
  s = wsum(s); sq = wsum(sq);
  float m = s * (1.0f / CC);
  float rs = rsqrtf(sq * (1.0f / CC) - m * m + 1e-5f);
  float4 ug = *(const float4*)(s_ng + c);
  float4 ub = *(const float4*)(s_nb + c);
  float o0 = (p.x - m) * rs * ug.x + ub.x;
  float o1 = (p.y - m) * rs * ug.y + ub.y;
  float o2 = (p.z - m) * rs * ug.z + ub.z;
  float o3 = (p.w - m) * rs * ug.w + ub.w;
  float gsg = sg[0];
  float x0 = xv.x + xs0 + gsg * o0;
  float x1 = xv.y + xs1 + gsg * o1;
  float x2 = xv.z + xs2 + gsg * o2;
  float x3 = xv.w + xs3 + gsg * o3;
  *(float4*)(X + off) = make_float4(x0, x1, x2, x3);
  float s2 = x0 + x1 + x2 + x3;
  float sq2 = x0 * x0 + x1 * x1 + x2 * x2 + x3 * x3;
  s2 = wsum(s2); sq2 = wsum(sq2);
  float m2 = s2 * (1.0f / CC);
  float rs2 = rsqrtf(sq2 * (1.0f / CC) - m2 * m2 + 1e-5f);
  float4 g2 = *(const float4*)(n2g + c);
  float4 b2 = *(const float4*)(n2b + c);
  ushort4 o;
  o.x = f2bf((x0 - m2) * rs2 * g2.x + b2.x);
  o.y = f2bf((x1 - m2) * rs2 * g2.y + b2.y);
  o.z = f2bf((x2 - m2) * rs2 * g2.z + b2.z);
  o.w = f2bf((x3 - m2) * rs2 * g2.w + b2.w);
  *(ushort4*)(A + off) = o;
}

// ---- 128x128-tile MFMA GEMM: out[M,Nc] = act[M,Kd](lda) @ Wt[Nc,Kd](ldb)^T ----
// grid = (Nc/128, M/128) with XCD-chunked swizzle. epi: 0 plain; 1 +bias; 2 +bias,gelu;
// 3 (+bias), Xacc += gamma*val (LDS-staged fp32, coalesced float4 RMW).
// K-loop: double-buffered LDS, raw s_barrier + counted waits (T3 minimum 2-phase).
__global__ __launch_bounds__(256) void k_gemm128(const u16* __restrict__ act, const u16* __restrict__ Wt,
                                                 const float* __restrict__ bias, const float* __restrict__ gptr,
                                                 u16* __restrict__ outB, float* __restrict__ Xacc,
                                                 int Kd, int Nc, int lda, int ldb, int epi, int remap) {
  __shared__ __align__(16) u16 smem[128 * 136];  // 34816 B: dbuf A/B (32 KB) aliases C-stage
  int gx = gridDim.x;
  int nwg = gx * gridDim.y;
  int lid = blockIdx.y * gx + blockIdx.x;
  if ((nwg & 7) == 0) lid = (lid & 7) * (nwg >> 3) + (lid >> 3);  // XCD-chunked (bijective: nwg%8==0)
  int m0 = (lid / gx) * 128, n0 = (lid % gx) * 128;
  int tid = threadIdx.x;
  int wv = tid >> 6, lane = tid & 63, lm = lane & 15, quad = lane >> 4;
  int wr = wv >> 1, wc = wv & 1;
  f32x4 acc[4][4];
#pragma unroll
  for (int i = 0; i < 4; i++)
#pragma unroll
    for (int j = 0; j < 4; j++) acc[i][j] = (f32x4){0.f, 0.f, 0.f, 0.f};

  // per-thread staging coords: cid = j*256 + tid; row = j*64 + (tid>>2); seg = tid&3
  const u16* pa = act + (long)(m0 + (tid >> 2)) * lda + (tid & 3) * 8;
  const u16* pb = Wt + (long)(n0 + (tid >> 2)) * ldb + (tid & 3) * 8;

  auto STAGE = [&](int buf, int kk) {
    u16* sb = smem + buf * 8192;  // [As | Bs] per buffer, 4096 u16 each
#pragma unroll
    for (int j = 0; j < 2; j++) {
      __builtin_amdgcn_global_load_lds(pa + (long)j * 64 * lda + kk, sb + (j * 256 + wv * 64) * 8, 16, 0, 0);
      __builtin_amdgcn_global_load_lds(pb + (long)j * 64 * ldb + kk, sb + 4096 + (j * 256 + wv * 64) * 8, 16, 0, 0);
    }
  };

  STAGE(0, 0);
  asm volatile("s_waitcnt vmcnt(0)" ::: "memory");
  __builtin_amdgcn_s_barrier();

  int nsteps = Kd >> 5;
  int cur = 0;
  for (int t = 0; t < nsteps; ++t) {
    if (t + 1 < nsteps) STAGE(cur ^ 1, (t + 1) << 5);   // prefetch next tile into other buffer
    const u16* As = smem + cur * 8192;
    const u16* Bs = As + 4096;
    bf16x8 af[4], bfv[4];
#pragma unroll
    for (int q = 0; q < 4; q++) {
      af[q] = *(const bf16x8*)&As[(wr * 64 + q * 16 + lm) * 32 + quad * 8];
      bfv[q] = *(const bf16x8*)&Bs[(wc * 64 + q * 16 + lm) * 32 + quad * 8];
    }
#pragma unroll
    for (int ti = 0; ti < 4; ti++)
#pragma unroll
      for (int tj = 0; tj < 4; tj++)
        acc[ti][tj] = __builtin_amdgcn_mfma_f32_16x16x32_bf16(af[ti], bfv[tj], acc[ti][tj], 0, 0, 0);
    asm volatile("s_waitcnt lgkmcnt(0)" ::: "memory");           // my ds_reads done -> buf[cur] reusable
    if (t + 1 < nsteps) asm volatile("s_waitcnt vmcnt(0)" ::: "memory");  // next tile landed (hidden under MFMA)
    __builtin_amdgcn_s_barrier();
    cur ^= 1;
  }

  if (epi == 3) {
    float gm = gptr ? gptr[0] : 1.0f;
    float* fs = (float*)smem;  // 64 x 132 fp32 = 33792 B
#pragma unroll
    for (int half = 0; half < 2; half++) {
      if (half) __syncthreads();
      if (wr == half) {
#pragma unroll
        for (int tj = 0; tj < 4; tj++) {
          int col = wc * 64 + tj * 16 + lm;
          float bv = bias ? bias[n0 + col] : 0.0f;
#pragma unroll
          for (int ti = 0; ti < 4; ti++)
#pragma unroll
            for (int r = 0; r < 4; r++)
              fs[(ti * 16 + quad * 4 + r) * 132 + col] = gm * (acc[ti][tj][r] + bv);
        }
      }
      __syncthreads();
      // coalesced float4 RMW of 64 rows x 128 cols
#pragma unroll
      for (int p = 0; p < 8; p++) {
        int idx = p * 256 + tid;            // 2048 float4 chunks
        int row = idx >> 5, c4 = idx & 31;
        int grow = remap_row(m0 + half * 64 + row, remap);
        float* gp = Xacc + (long)grow * Nc + n0 + c4 * 4;
        float4 xv = *(float4*)gp;
        float4 sv = *(const float4*)&fs[row * 132 + c4 * 4];
        xv.x += sv.x; xv.y += sv.y; xv.z += sv.z; xv.w += sv.w;
        *(float4*)gp = xv;
      }
    }
  } else {
    // stage C in LDS (row stride 136 u16 de-conflicts banks), then coalesced uint4 writes
#pragma unroll
    for (int tj = 0; tj < 4; tj++) {
      int col = wc * 64 + tj * 16 + lm;
      float bv = (epi >= 1 && bias) ? bias[n0 + col] : 0.0f;
#pragma unroll
      for (int ti = 0; ti < 4; ti++)
#pragma unroll
        for (int r = 0; r < 4; r++) {
          float vv = acc[ti][tj][r] + bv;
          if (epi == 2) vv = gelu_f(vv);
          smem[(wr * 64 + ti * 16 + quad * 4 + r) * 136 + col] = f2bf(vv);
        }
    }
    __syncthreads();
#pragma unroll
    for (int p = 0; p < 8; p++) {
      int idx = p * 256 + tid;             // 2048 uint4 chunks of the 128x128 tile
      int row = idx >> 4, c8 = idx & 15;
      int grow = remap_row(m0 + row, remap);
      *(uint4*)(outB + (long)grow * Nc + n0 + c8 * 8) = *(const uint4*)&smem[row * 136 + c8 * 8];
    }
  }
}

// ---- spatial attention: per (b,t,h); QKV interleaved [N,768]; S=(QK^T*adj+1)/2; O=S@V -> O[N,256] ----
__global__ __launch_bounds__(384) void k_sp_attn(const u16* __restrict__ QKV, const u16* __restrict__ adj,
                                                 u16* __restrict__ O) {
  __shared__ __align__(16) u16 Qs[96 * 32];
  __shared__ __align__(16) u16 Ks[96 * 32];
  __shared__ __align__(16) u16 Vs[96 * 32];
  __shared__ __align__(16) u16 Ss[96 * 96];
  int blk = blockIdx.x;
  blk = (blk & 7) * ((int)gridDim.x >> 3) + (blk >> 3);  // XCD-chunked: 8 heads of one (b,t) share QKV rows
  int h = blk & 7, t = (blk >> 3) % TT, b = blk / (8 * TT);
  long base = ((long)(b * TT + t) * EE) * 768 + h * DDm;
  int tid = threadIdx.x;
  {
    int row = tid >> 2, seg = tid & 3;
    long goff = base + (long)row * 768 + seg * 8;
    *(uint4*)&Qs[row * 32 + seg * 8] = *(const uint4*)(QKV + goff);
    *(uint4*)&Ks[row * 32 + seg * 8] = *(const uint4*)(QKV + goff + 256);
    *(uint4*)&Vs[row * 32 + seg * 8] = *(const uint4*)(QKV + goff + 512);
#pragma unroll
    for (int i = 0; i < 3; i++) {
      int off = tid * 24 + i * 8;
      *(uint4*)&Ss[off] = *(const uint4*)(adj + off);
    }
  }
  __syncthreads();
  int wv = tid >> 6, lane = tid & 63, lm = lane & 15, quad = lane >> 4;
  bf16x8 aq = *(const bf16x8*)&Qs[(wv * 16 + lm) * 32 + quad * 8];
  f32x4 sc[6];
#pragma unroll
  for (int j = 0; j < 6; j++) {
    bf16x8 bk = *(const bf16x8*)&Ks[(j * 16 + lm) * 32 + quad * 8];
    f32x4 z = (f32x4){0.f, 0.f, 0.f, 0.f};
    sc[j] = __builtin_amdgcn_mfma_f32_16x16x32_bf16(aq, bk, z, 0, 0, 0);
  }
  u16 sv[6][4];
#pragma unroll
  for (int j = 0; j < 6; j++) {
    int col = j * 16 + lm;
#pragma unroll
    for (int r = 0; r < 4; r++) {
      int row = wv * 16 + quad * 4 + r;
      float a = bf2f(Ss[row * 96 + col]);
      sv[j][r] = f2bf((sc[j][r] * a + 1.0f) * 0.5f);
    }
  }
  __syncthreads();
#pragma unroll
  for (int j = 0; j < 6; j++) {
    int col = j * 16 + lm;
#pragma unroll
    for (int r = 0; r < 4; r++) Ss[(wv * 16 + quad * 4 + r) * 96 + col] = sv[j][r];
  }
  __syncthreads();
  f32x4 oc[2];
  oc[0] = (f32x4){0.f, 0.f, 0.f, 0.f};
  oc[1] = (f32x4){0.f, 0.f, 0.f, 0.f};
#pragma unroll
  for (int ks = 0; ks < 3; ks++) {
    bf16x8 as = *(const bf16x8*)&Ss[(wv * 16 + lm) * 96 + ks * 32 + quad * 8];
#pragma unroll
    for (int n = 0; n < 2; n++) {
      bf16x8 bv;
#pragma unroll
      for (int jj = 0; jj < 8; jj++)
        bv[jj] = (short)Vs[(ks * 32 + quad * 8 + jj) * 32 + n * 16 + lm];
      oc[n] = __builtin_amdgcn_mfma_f32_16x16x32_bf16(as, bv, oc[n], 0, 0, 0);
    }
  }
  long obase = ((long)(b * TT + t) * EE) * CC + h * DDm;
#pragma unroll
  for (int n = 0; n < 2; n++)
#pragma unroll
    for (int r = 0; r < 4; r++) {
      int row = wv * 16 + quad * 4 + r;
      O[obase + (long)row * CC + n * 16 + lm] = f2bf(oc[n][r]);
    }
}

// ---- temporal attention: per (b,e,h); QKV [b,e,t] [N,768]; register softmax; O [b,e,t] [N,256] ----
__global__ __launch_bounds__(384) void k_tp_attn(const u16* __restrict__ QKV, u16* __restrict__ O) {
  __shared__ __align__(16) u16 Qs[96 * 32];
  __shared__ __align__(16) u16 Ks[96 * 32];
  __shared__ __align__(16) u16 Vs[96 * 32];
  __shared__ __align__(16) u16 Ss[96 * 96];   // P in bf16
  int blk = blockIdx.x;
  blk = (blk & 7) * ((int)gridDim.x >> 3) + (blk >> 3);  // XCD-chunked
  int h = blk & 7, e = (blk >> 3) % EE, b = blk / (8 * EE);
  long base = ((long)(b * EE + e) * TT) * 768 + h * DDm;
  int tid = threadIdx.x;
  {
    int row = tid >> 2, seg = tid & 3;
    long goff = base + (long)row * 768 + seg * 8;
    *(uint4*)&Qs[row * 32 + seg * 8] = *(const uint4*)(QKV + goff);
    *(uint4*)&Ks[row * 32 + seg * 8] = *(const uint4*)(QKV + goff + 256);
    *(uint4*)&Vs[row * 32 + seg * 8] = *(const uint4*)(QKV + goff + 512);
  }
  __syncthreads();
  int wv = tid >> 6, lane = tid & 63, lm = lane & 15, quad = lane >> 4;
  bf16x8 aq = *(const bf16x8*)&Qs[(wv * 16 + lm) * 32 + quad * 8];
  f32x4 sc[6];
#pragma unroll
  for (int j = 0; j < 6; j++) {
    bf16x8 bk = *(const bf16x8*)&Ks[(j * 16 + lm) * 32 + quad * 8];
    f32x4 z = (f32x4){0.f, 0.f, 0.f, 0.f};
    sc[j] = __builtin_amdgcn_mfma_f32_16x16x32_bf16(aq, bk, z, 0, 0, 0);
  }
  const float scale = 0.17677669529663687f;  // 1/sqrt(32)
#pragma unroll
  for (int r = 0; r < 4; r++) {
    float mx = -1e30f;
#pragma unroll
    for (int j = 0; j < 6; j++) { sc[j][r] *= scale; mx = fmaxf(mx, sc[j][r]); }
#pragma unroll
    for (int mask = 1; mask < 16; mask <<= 1) mx = fmaxf(mx, __shfl_xor(mx, mask));
    float sum = 0.f;
#pragma unroll
    for (int j = 0; j < 6; j++) { float p = __expf(sc[j][r] - mx); sc[j][r] = p; sum += p; }
#pragma unroll
    for (int mask = 1; mask < 16; mask <<= 1) sum += __shfl_xor(sum, mask);
    float inv = 1.0f / sum;
#pragma unroll
    for (int j = 0; j < 6; j++) sc[j][r] *= inv;
  }
#pragma unroll
  for (int j = 0; j < 6; j++) {
    int col = j * 16 + lm;
#pragma unroll
    for (int r = 0; r < 4; r++) Ss[(wv * 16 + quad * 4 + r) * 96 + col] = f2bf(sc[j][r]);
  }
  __syncthreads();
  f32x4 oc[2];
  oc[0] = (f32x4){0.f, 0.f, 0.f, 0.f};
  oc[1] = (f32x4){0.f, 0.f, 0.f, 0.f};
#pragma unroll
  for (int ks = 0; ks < 3; ks++) {
    bf16x8 as = *(const bf16x8*)&Ss[(wv * 16 + lm) * 96 + ks * 32 + quad * 8];
#pragma unroll
    for (int n = 0; n < 2; n++) {
      bf16x8 bv;
#pragma unroll
      for (int jj = 0; jj < 8; jj++)
        bv[jj] = (short)Vs[(ks * 32 + quad * 8 + jj) * 32 + n * 16 + lm];
      oc[n] = __builtin_amdgcn_mfma_f32_16x16x32_bf16(as, bv, oc[n], 0, 0, 0);
    }
  }
  long obase = ((long)(b * EE + e) * TT) * CC + h * DDm;
#pragma unroll
  for (int n = 0; n < 2; n++)
#pragma unroll
    for (int r = 0; r < 4; r++) {
      int row = wv * 16 + quad * 4 + r;  // t index
      O[obase + (long)row * CC + n * 16 + lm] = f2bf(oc[n][r]);
    }
}

// ------- downsample: out[b,i,e,c] = 0.5*(X[b,2i,e,c] + X[b,2i+1,e,c])  (fp32 out) -------
__global__ __launch_bounds__(256) void k_down(const float* __restrict__ X, float* __restrict__ out) {
  long i4 = ((long)blockIdx.x * 256 + threadIdx.x) * 4;
  long tmp = i4;
  int c = (int)(tmp & 255); tmp >>= 8;
  int e = (int)(tmp % EE); tmp /= EE;
  int i = (int)(tmp % TOUT);
  int b = (int)(tmp / TOUT);
  long src0 = (((long)b * TT + 2 * i) * EE + e) * CC + c;
  float4 a = *(const float4*)(X + src0);
  float4 bb = *(const float4*)(X + src0 + (long)EE * CC);
  float4 o = make_float4(0.5f * (a.x + bb.x), 0.5f * (a.y + bb.y),
                         0.5f * (a.z + bb.z), 0.5f * (a.w + bb.w));
  *(float4*)(out + i4) = o;
}

extern "C" void kernel_launch(void* const* d_in, const int* in_sizes, int n_in,
                              void* d_out, int out_size, void* d_ws, size_t ws_size,
                              hipStream_t stream) {
  (void)in_sizes; (void)n_in; (void)out_size; (void)ws_size;
  const float* x   = (const float*)d_in[0];
  const float* adj = (const float*)d_in[1];
  const float* n1g = (const float*)d_in[2];
  const float* n1b = (const float*)d_in[3];
  const float* swq = (const float*)d_in[4];
  const float* swk = (const float*)d_in[5];
  const float* swv = (const float*)d_in[6];
  const float* swp = (const float*)d_in[7];
  const float* sbp = (const float*)d_in[8];
  const float* sng = (const float*)d_in[9];
  const float* snb = (const float*)d_in[10];
  const float* sg  = (const float*)d_in[11];
  const float* n2g = (const float*)d_in[12];
  const float* n2b = (const float*)d_in[13];
  const float* twq = (const float*)d_in[14];
  const float* twk = (const float*)d_in[15];
  const float* twv = (const float*)d_in[16];
  const float* twp = (const float*)d_in[17];
  const float* tbp = (const float*)d_in[18];
  const float* tg  = (const float*)d_in[19];
  const float* n3g = (const float*)d_in[20];
  const float* n3b = (const float*)d_in[21];
  const float* mw1 = (const float*)d_in[22];
  const float* mb1 = (const float*)d_in[23];
  const float* mw2 = (const float*)d_in[24];
  const float* mb2 = (const float*)d_in[25];
  float* out = (float*)d_out;

  // ---- workspace: X fp32 | A bf16 | QKV bf16 [N,768] | weights ----
  size_t nc = (size_t)NTOK * CC;
  float* X  = (float*)d_ws;
  u16* A    = (u16*)(X + nc);
  u16* QKV  = A + nc;
  u16* Pb   = QKV;
  u16* Hh   = QKV;    // MLP: [N/2, 1024] = 75.5 MB fits in QKV (113 MB)
  u16* wts  = QKV + 3 * nc;
  u16* swq_t = wts;
  u16* swp_t = wts + 3 * 65536;
  u16* twq_t = wts + 4 * 65536;
  u16* twp_t = wts + 7 * 65536;
  u16* w1_t  = wts + 8 * 65536;  // [1024,256]
  u16* w2_t  = w1_t + 262144;    // [256,1024]
  u16* adj_b = w2_t + 262144;    // [96,96]

  WPtr8 w8; w8.p[0] = swq; w8.p[1] = swk; w8.p[2] = swv; w8.p[3] = swp;
  w8.p[4] = twq; w8.p[5] = twk; w8.p[6] = twv; w8.p[7] = twp;
  k_transpose8<<<dim3(256, 8), 256, 0, stream>>>(w8, wts);
  k_transpose<<<(256 * 1024 + 255) / 256, 256, 0, stream>>>(mw1, w1_t, 256, 1024, 256 * 1024);
  k_transpose<<<(1024 * 256 + 255) / 256, 256, 0, stream>>>(mw2, w2_t, 1024, 256, 1024 * 256);
  k_cvt<<<(EE * EE + 255) / 256, 256, 0, stream>>>(adj, adj_b, EE * EE);

  auto gemm = [&](const u16* act, const u16* Wt, const float* bias, const float* gamma,
                  u16* outB, float* Xacc, int Kd, int Nc, int lda, int ldb, int epi, int remap, int M) {
    dim3 g(Nc / 128, M / 128);
    k_gemm128<<<g, 256, 0, stream>>>(act, Wt, bias, gamma, outB, Xacc, Kd, Nc, lda, ldb, epi, remap);
  };

  int lnBlocks = NTOK / 4;

  // ---- spatial block ----
  k_ln_in<<<lnBlocks, 256, 0, stream>>>(x, A, n1g, n1b);                          // A = xs
  gemm(A, swq_t, nullptr, nullptr, QKV, nullptr, 256, 768, 256, 256, 0, 0, NTOK); // fused QKV
  k_sp_attn<<<BB * TT * HHD, 384, 0, stream>>>(QKV, adj_b, A);                    // O -> A
  gemm(A, swp_t, sbp, nullptr, Pb, nullptr, 256, 256, 256, 256, 1, 0, NTOK);      // P -> Pb
  k_sp_combine<<<lnBlocks, 256, 0, stream>>>(x, X, A, Pb, n1g, n1b, sg, sng, snb, n2g, n2b);

  // ---- temporal block (token order [b,e,t] inside) ----
  gemm(A, twq_t, nullptr, nullptr, QKV, nullptr, 256, 768, 256, 256, 0, 1, NTOK); // fused QKV, bte->bet
  k_tp_attn<<<BB * EE * HHD, 384, 0, stream>>>(QKV, A);                           // O -> A (bet)
  gemm(A, twp_t, tbp, tg, nullptr, X, 256, 256, 256, 256, 3, 2, NTOK);            // X += g*(O@wp+b), bet->bte

  // ---- MLP: token-split halves, full HID=1024 each (X RMW once per token) ----
  k_ln_f32<<<lnBlocks, 256, 0, stream>>>(X, A, n3g, n3b);                         // A = xm
  for (int hf = 0; hf < 2; hf++) {
    long r0 = (long)hf * (NTOK / 2);
    gemm(A + r0 * CC, w1_t, mb1, nullptr, Hh, nullptr, 256, 1024, 256, 256, 2, 0, NTOK / 2);
    gemm(Hh, w2_t, mb2, nullptr, nullptr, X + r0 * CC, 1024, 256, 1024, 1024, 3, 0, NTOK / 2);
  }

  // ---- downsample (fp32 out) ----
  long outElems = (long)BB * TOUT * EE * CC;
  k_down<<<(int)(outElems / 4 / 256), 256, 0, stream>>>(X, out);
}

// Round 3
// 671.571 us; speedup vs baseline: 1.2072x; 1.0393x over previous
//
#include <hip/hip_runtime.h>
#include <cmath>

constexpr int BB = 8, TT = 96, EE = 96, CC = 256, HHD = 8, DDm = 32;
constexpr int NTOK = BB * TT * EE;   // 73728
constexpr int TOUT = TT / 2;         // 48

typedef unsigned short u16;
typedef short bf16x8 __attribute__((ext_vector_type(8)));
typedef float f32x4 __attribute__((ext_vector_type(4)));

__device__ __forceinline__ float bf2f(u16 u) {
  union { unsigned int i; float f; } v; v.i = ((unsigned int)u) << 16; return v.f;
}
__device__ __forceinline__ u16 f2bf(float f) {
  union { unsigned int i; float f; } v; v.f = f;
  return (u16)((v.i + 0x7FFFu + ((v.i >> 16) & 1u)) >> 16);  // RNE
}
__device__ __forceinline__ float wsum(float v) {
#pragma unroll
  for (int off = 32; off; off >>= 1) v += __shfl_xor(v, off);
  return v;
}
__device__ __forceinline__ float gelu_f(float x) {
  return 0.5f * x * (1.0f + erff(x * 0.70710678118654752f));
}
// token-order permutations: 0=id, 1=[b,t,e]->[b,e,t] position, 2=[b,e,t]->[b,t,e]
__device__ __forceinline__ int remap_row(int row, int mode) {
  if (mode == 0) return row;
  int b = row / (TT * EE);
  int rem = row - b * (TT * EE);
  if (mode == 1) { int t = rem / EE, e = rem - t * EE; return (b * EE + e) * TT + t; }
  int e = rem / TT, t = rem - e * TT;
  return (b * TT + t) * EE + e;
}

// -------- batched weight transpose+convert: 8 x [256,256] fp32 -> bf16 [Nc][K] --------
struct WPtr8 { const float* p[8]; };
__global__ void k_transpose8(WPtr8 src, u16* __restrict__ dst) {
  const float* in = src.p[blockIdx.y];
  u16* out = dst + (size_t)blockIdx.y * 65536;
  int idx = blockIdx.x * 256 + threadIdx.x;
  int k = idx >> 8, c = idx & 255;
  out[c * 256 + k] = f2bf(in[idx]);
}

// -------- weight transpose+convert: W fp32 [K][Nc] -> Wt bf16 [Nc][K] --------
__global__ void k_transpose(const float* __restrict__ in, u16* __restrict__ out, int K, int Nc, int n) {
  int idx = blockIdx.x * 256 + threadIdx.x;
  if (idx < n) {
    int k = idx / Nc, c = idx - k * Nc;
    out[c * K + k] = f2bf(in[idx]);
  }
}

// -------- fp32 -> bf16 convert (adj) --------
__global__ void k_cvt(const float* __restrict__ in, u16* __restrict__ out, int n) {
  int idx = blockIdx.x * 256 + threadIdx.x;
  if (idx < n) out[idx] = f2bf(in[idx]);
}

// ------- LN of fp32 input x -> A = LN(x)*g+b (bf16); no X copy -------
__global__ __launch_bounds__(256) void k_ln_in(const float* __restrict__ x,
                                               u16* __restrict__ A, const float* __restrict__ g,
                                               const float* __restrict__ b) {
  int wv = threadIdx.x >> 6, lane = threadIdx.x & 63;
  long tok = (long)blockIdx.x * 4 + wv;
  int c = lane * 4;
  long off = tok * CC + c;
  float4 v = *(const float4*)(x + off);
  float s = v.x + v.y + v.z + v.w;
  float sq = v.x * v.x + v.y * v.y + v.z * v.z + v.w * v.w;
  s = wsum(s); sq = wsum(sq);
  float m = s * (1.0f / CC);
  float rs = rsqrtf(sq * (1.0f / CC) - m * m + 1e-5f);
  float4 gv = *(const float4*)(g + c);
  float4 bv = *(const float4*)(b + c);
  ushort4 o;
  o.x = f2bf((v.x - m) * rs * gv.x + bv.x);
  o.y = f2bf((v.y - m) * rs * gv.y + bv.y);
  o.z = f2bf((v.z - m) * rs * gv.z + bv.z);
  o.w = f2bf((v.w - m) * rs * gv.w + bv.w);
  *(ushort4*)(A + off) = o;
}

// ---------------- A = LN(X fp32)*g+b ----------------
__global__ __launch_bounds__(256) void k_ln_f32(const float* __restrict__ X, u16* __restrict__ A,
                                                const float* __restrict__ g, const float* __restrict__ b) {
  int wv = threadIdx.x >> 6, lane = threadIdx.x & 63;
  long tok = (long)blockIdx.x * 4 + wv;
  int c = lane * 4;
  long off = tok * CC + c;
  float4 v = *(const float4*)(X + off);
  float s = v.x + v.y + v.z + v.w;
  float sq = v.x * v.x + v.y * v.y + v.z * v.z + v.w * v.w;
  s = wsum(s); sq = wsum(sq);
  float m = s * (1.0f / CC);
  float rs = rsqrtf(sq * (1.0f / CC) - m * m + 1e-5f);
  float4 gv = *(const float4*)(g + c);
  float4 bv = *(const float4*)(b + c);
  ushort4 o;
  o.x = f2bf((v.x - m) * rs * gv.x + bv.x);
  o.y = f2bf((v.y - m) * rs * gv.y + bv.y);
  o.z = f2bf((v.z - m) * rs * gv.z + bv.z);
  o.w = f2bf((v.w - m) * rs * gv.w + bv.w);
  *(ushort4*)(A + off) = o;
}

// ------- spatial combine: reads pristine x; xs = LN1(x); o = LN(P)*s_ng+s_nb;
//         X = x + xs + s_gamma*o (first write of X); A = LN2(X) -------
__global__ __launch_bounds__(256) void k_sp_combine(const float* __restrict__ xin, float* __restrict__ X,
                                                    u16* __restrict__ A, const u16* __restrict__ P,
                                                    const float* __restrict__ n1g, const float* __restrict__ n1b,
                                                    const float* __restrict__ sg,
                                                    const float* __restrict__ s_ng, const float* __restrict__ s_nb,
                                                    const float* __restrict__ n2g, const float* __restrict__ n2b) {
  int wv = threadIdx.x >> 6, lane = threadIdx.x & 63;
  long tok = (long)blockIdx.x * 4 + wv;
  int c = lane * 4;
  long off = tok * CC + c;
  float4 xv = *(const float4*)(xin + off);
  float s1 = xv.x + xv.y + xv.z + xv.w;
  float q1 = xv.x * xv.x + xv.y * xv.y + xv.z * xv.z + xv.w * xv.w;
  s1 = wsum(s1); q1 = wsum(q1);
  float m1 = s1 * (1.0f / CC);
  float r1 = rsqrtf(q1 * (1.0f / CC) - m1 * m1 + 1e-5f);
  float4 g1 = *(const float4*)(n1g + c);
  float4 b1 = *(const float4*)(n1b + c);
  float xs0 = (xv.x - m1) * r1 * g1.x + b1.x;
  float xs1 = (xv.y - m1) * r1 * g1.y + b1.y;
  float xs2 = (xv.z - m1) * r1 * g1.z + b1.z;
  float xs3 = (xv.w - m1) * r1 * g1.w + b1.w;
  ushort4 up = *(const ushort4*)(P + off);
  float4 p = make_float4(bf2f(up.x), bf2f(up.y), bf2f(up.z), bf2f(up.w));
  float s = p.x + p.y + p.z + p.w;
  float sq = p.x * p.x + p.y * p.y + p.z * p.z + p.w * p.w;
  s = wsum(s); sq = wsum(sq);
  float m = s * (1.0f / CC);
  float rs = rsqrtf(sq * (1.0f / CC) - m * m + 1e-5f);
  float4 ug = *(const float4*)(s_ng + c);
  float4 ub = *(const float4*)(s_nb + c);
  float o0 = (p.x - m) * rs * ug.x + ub.x;
  float o1 = (p.y - m) * rs * ug.y + ub.y;
  float o2 = (p.z - m) * rs * ug.z + ub.z;
  float o3 = (p.w - m) * rs * ug.w + ub.w;
  float gsg = sg[0];
  float x0 = xv.x + xs0 + gsg * o0;
  float x1 = xv.y + xs1 + gsg * o1;
  float x2 = xv.z + xs2 + gsg * o2;
  float x3 = xv.w + xs3 + gsg * o3;
  *(float4*)(X + off) = make_float4(x0, x1, x2, x3);
  float s2 = x0 + x1 + x2 + x3;
  float sq2 = x0 * x0 + x1 * x1 + x2 * x2 + x3 * x3;
  s2 = wsum(s2); sq2 = wsum(sq2);
  float m2 = s2 * (1.0f / CC);
  float rs2 = rsqrtf(sq2 * (1.0f / CC) - m2 * m2 + 1e-5f);
  float4 g2 = *(const float4*)(n2g + c);
  float4 b2 = *(const float4*)(n2b + c);
  ushort4 o;
  o.x = f2bf((x0 - m2) * rs2 * g2.x + b2.x);
  o.y = f2bf((x1 - m2) * rs2 * g2.y + b2.y);
  o.z = f2bf((x2 - m2) * rs2 * g2.z + b2.z);
  o.w = f2bf((x3 - m2) * rs2 * g2.w + b2.w);
  *(ushort4*)(A + off) = o;
}

// ---- 128x128-tile MFMA GEMM: out[M,Nc] = act[M,Kd](lda) @ Wt[Nc,Kd](ldb)^T ----
// grid = (Nc/128, M/128) with XCD-chunked swizzle. epi: 0 plain; 1 +bias; 2 +bias,gelu;
// 3 (+bias), Xacc += gamma*val (LDS-staged fp32, coalesced float4 RMW).
// K-loop: 3-buffer LDS, depth-2 prefetch, counted vmcnt(4) (T3/T4), XOR seg-swizzle (T2,
// rule-21: linear LDS dest + inverse-swizzled global source + swizzled ds_read), setprio (T5).
__global__ __launch_bounds__(256) void k_gemm128(const u16* __restrict__ act, const u16* __restrict__ Wt,
                                                 const float* __restrict__ bias, const float* __restrict__ gptr,
                                                 u16* __restrict__ outB, float* __restrict__ Xacc,
                                                 int Kd, int Nc, int lda, int ldb, int epi, int remap) {
  __shared__ __align__(16) u16 smem[3 * 8192];   // 49152 B: 3 x (As 4096 + Bs 4096); epilogue aliases
  int gx = gridDim.x;
  int nwg = gx * gridDim.y;
  int lid = blockIdx.y * gx + blockIdx.x;
  if ((nwg & 7) == 0) lid = (lid & 7) * (nwg >> 3) + (lid >> 3);  // XCD-chunked (bijective: nwg%8==0)
  int m0 = (lid / gx) * 128, n0 = (lid % gx) * 128;
  int tid = threadIdx.x;
  int wv = tid >> 6, lane = tid & 63, lm = lane & 15, quad = lane >> 4;
  int wr = wv >> 1, wc = wv & 1;
  f32x4 acc[4][4];
#pragma unroll
  for (int i = 0; i < 4; i++)
#pragma unroll
    for (int j = 0; j < 4; j++) acc[i][j] = (f32x4){0.f, 0.f, 0.f, 0.f};

  // staging: chunk cid = j*256 + tid -> LDS (row = j*64 + (tid>>2), slot = tid&3), linear dest.
  // source seg pre-swizzled: seg = (tid&3) ^ ((srow>>1)&3); j*64 contributes 0 mod 4 on both sides.
  int srow = tid >> 2;
  int sseg = (tid & 3) ^ ((srow >> 1) & 3);
  const u16* pa = act + (long)(m0 + srow) * lda + sseg * 8;
  const u16* pb = Wt + (long)(n0 + srow) * ldb + sseg * 8;

  auto STAGE = [&](int buf, int kk) {
    u16* sb = smem + buf * 8192;  // [As | Bs] per buffer, 4096 u16 each
#pragma unroll
    for (int j = 0; j < 2; j++) {
      __builtin_amdgcn_global_load_lds(pa + (long)j * 64 * lda + kk, sb + (j * 256 + wv * 64) * 8, 16, 0, 0);
      __builtin_amdgcn_global_load_lds(pb + (long)j * 64 * ldb + kk, sb + 4096 + (j * 256 + wv * 64) * 8, 16, 0, 0);
    }
  };

  int nsteps = Kd >> 5;              // always >= 8 here
  STAGE(0, 0);
  STAGE(1, 32);
  asm volatile("s_waitcnt vmcnt(4)" ::: "memory");   // tile0 landed; tile1 in flight
  __builtin_amdgcn_sched_barrier(0);
  __builtin_amdgcn_s_barrier();

  int xsw = (lm >> 1) & 3;           // read-side swizzle: slot = quad ^ xsw (involution of source swizzle)
  int cur = 0;
  for (int t = 0; t < nsteps; ++t) {
    if (t + 2 < nsteps) {
      int nb = cur + 2; if (nb >= 3) nb -= 3;
      STAGE(nb, (t + 2) << 5);       // depth-2 prefetch
    }
    const u16* As = smem + cur * 8192;
    const u16* Bs = As + 4096;
    bf16x8 af[4], bfv[4];
#pragma unroll
    for (int q = 0; q < 4; q++) {
      af[q] = *(const bf16x8*)&As[(wr * 64 + q * 16 + lm) * 32 + (quad ^ xsw) * 8];
      bfv[q] = *(const bf16x8*)&Bs[(wc * 64 + q * 16 + lm) * 32 + (quad ^ xsw) * 8];
    }
    __builtin_amdgcn_s_setprio(1);
#pragma unroll
    for (int ti = 0; ti < 4; ti++)
#pragma unroll
      for (int tj = 0; tj < 4; tj++)
        acc[ti][tj] = __builtin_amdgcn_mfma_f32_16x16x32_bf16(af[ti], bfv[tj], acc[ti][tj], 0, 0, 0);
    __builtin_amdgcn_s_setprio(0);
    asm volatile("s_waitcnt lgkmcnt(0)" ::: "memory");          // my ds_reads done -> buf reusable
    __builtin_amdgcn_sched_barrier(0);
    if (t + 2 < nsteps) asm volatile("s_waitcnt vmcnt(4)" ::: "memory");  // tile t+1 landed (t+2 stays in flight)
    else                asm volatile("s_waitcnt vmcnt(0)" ::: "memory");  // drain tail
    __builtin_amdgcn_sched_barrier(0);
    __builtin_amdgcn_s_barrier();
    cur += 1; if (cur >= 3) cur -= 3;
  }

  if (epi == 3) {
    float gm = gptr ? gptr[0] : 1.0f;
    float* fs = (float*)smem;  // 64 x 132 fp32 = 33792 B
#pragma unroll
    for (int half = 0; half < 2; half++) {
      if (half) __syncthreads();
      if (wr == half) {
#pragma unroll
        for (int tj = 0; tj < 4; tj++) {
          int col = wc * 64 + tj * 16 + lm;
          float bv = bias ? bias[n0 + col] : 0.0f;
#pragma unroll
          for (int ti = 0; ti < 4; ti++)
#pragma unroll
            for (int r = 0; r < 4; r++)
              fs[(ti * 16 + quad * 4 + r) * 132 + col] = gm * (acc[ti][tj][r] + bv);
        }
      }
      __syncthreads();
      // coalesced float4 RMW of 64 rows x 128 cols
#pragma unroll
      for (int p = 0; p < 8; p++) {
        int idx = p * 256 + tid;            // 2048 float4 chunks
        int row = idx >> 5, c4 = idx & 31;
        int grow = remap_row(m0 + half * 64 + row, remap);
        float* gp = Xacc + (long)grow * Nc + n0 + c4 * 4;
        float4 xv = *(float4*)gp;
        float4 sv = *(const float4*)&fs[row * 132 + c4 * 4];
        xv.x += sv.x; xv.y += sv.y; xv.z += sv.z; xv.w += sv.w;
        *(float4*)gp = xv;
      }
    }
  } else {
    // stage C in LDS (row stride 136 u16 de-conflicts banks), then coalesced uint4 writes
#pragma unroll
    for (int tj = 0; tj < 4; tj++) {
      int col = wc * 64 + tj * 16 + lm;
      float bv = (epi >= 1 && bias) ? bias[n0 + col] : 0.0f;
#pragma unroll
      for (int ti = 0; ti < 4; ti++)
#pragma unroll
        for (int r = 0; r < 4; r++) {
          float vv = acc[ti][tj][r] + bv;
          if (epi == 2) vv = gelu_f(vv);
          smem[(wr * 64 + ti * 16 + quad * 4 + r) * 136 + col] = f2bf(vv);
        }
    }
    __syncthreads();
#pragma unroll
    for (int p = 0; p < 8; p++) {
      int idx = p * 256 + tid;             // 2048 uint4 chunks of the 128x128 tile
      int row = idx >> 4, c8 = idx & 15;
      int grow = remap_row(m0 + row, remap);
      *(uint4*)(outB + (long)grow * Nc + n0 + c8 * 8) = *(const uint4*)&smem[row * 136 + c8 * 8];
    }
  }
}

// ---- spatial attention: per (b,t,h); QKV interleaved [N,768]; S=(QK^T*adj+1)/2; O=S@V -> O[N,256] ----
__global__ __launch_bounds__(384) void k_sp_attn(const u16* __restrict__ QKV, const u16* __restrict__ adj,
                                                 u16* __restrict__ O) {
  __shared__ __align__(16) u16 Qs[96 * 32];
  __shared__ __align__(16) u16 Ks[96 * 32];
  __shared__ __align__(16) u16 Vs[96 * 32];
  __shared__ __align__(16) u16 Ss[96 * 96];
  int blk = blockIdx.x;
  blk = (blk & 7) * ((int)gridDim.x >> 3) + (blk >> 3);  // XCD-chunked: 8 heads of one (b,t) share QKV rows
  int h = blk & 7, t = (blk >> 3) % TT, b = blk / (8 * TT);
  long base = ((long)(b * TT + t) * EE) * 768 + h * DDm;
  int tid = threadIdx.x;
  {
    int row = tid >> 2, seg = tid & 3;
    long goff = base + (long)row * 768 + seg * 8;
    *(uint4*)&Qs[row * 32 + seg * 8] = *(const uint4*)(QKV + goff);
    *(uint4*)&Ks[row * 32 + seg * 8] = *(const uint4*)(QKV + goff + 256);
    *(uint4*)&Vs[row * 32 + seg * 8] = *(const uint4*)(QKV + goff + 512);
#pragma unroll
    for (int i = 0; i < 3; i++) {
      int off = tid * 24 + i * 8;
      *(uint4*)&Ss[off] = *(const uint4*)(adj + off);
    }
  }
  __syncthreads();
  int wv = tid >> 6, lane = tid & 63, lm = lane & 15, quad = lane >> 4;
  bf16x8 aq = *(const bf16x8*)&Qs[(wv * 16 + lm) * 32 + quad * 8];
  f32x4 sc[6];
#pragma unroll
  for (int j = 0; j < 6; j++) {
    bf16x8 bk = *(const bf16x8*)&Ks[(j * 16 + lm) * 32 + quad * 8];
    f32x4 z = (f32x4){0.f, 0.f, 0.f, 0.f};
    sc[j] = __builtin_amdgcn_mfma_f32_16x16x32_bf16(aq, bk, z, 0, 0, 0);
  }
  u16 sv[6][4];
#pragma unroll
  for (int j = 0; j < 6; j++) {
    int col = j * 16 + lm;
#pragma unroll
    for (int r = 0; r < 4; r++) {
      int row = wv * 16 + quad * 4 + r;
      float a = bf2f(Ss[row * 96 + col]);
      sv[j][r] = f2bf((sc[j][r] * a + 1.0f) * 0.5f);
    }
  }
  __syncthreads();
#pragma unroll
  for (int j = 0; j < 6; j++) {
    int col = j * 16 + lm;
#pragma unroll
    for (int r = 0; r < 4; r++) Ss[(wv * 16 + quad * 4 + r) * 96 + col] = sv[j][r];
  }
  __syncthreads();
  f32x4 oc[2];
  oc[0] = (f32x4){0.f, 0.f, 0.f, 0.f};
  oc[1] = (f32x4){0.f, 0.f, 0.f, 0.f};
#pragma unroll
  for (int ks = 0; ks < 3; ks++) {
    bf16x8 as = *(const bf16x8*)&Ss[(wv * 16 + lm) * 96 + ks * 32 + quad * 8];
#pragma unroll
    for (int n = 0; n < 2; n++) {
      bf16x8 bv;
#pragma unroll
      for (int jj = 0; jj < 8; jj++)
        bv[jj] = (short)Vs[(ks * 32 + quad * 8 + jj) * 32 + n * 16 + lm];
      oc[n] = __builtin_amdgcn_mfma_f32_16x16x32_bf16(as, bv, oc[n], 0, 0, 0);
    }
  }
  long obase = ((long)(b * TT + t) * EE) * CC + h * DDm;
#pragma unroll
  for (int n = 0; n < 2; n++)
#pragma unroll
    for (int r = 0; r < 4; r++) {
      int row = wv * 16 + quad * 4 + r;
      O[obase + (long)row * CC + n * 16 + lm] = f2bf(oc[n][r]);
    }
}

// ---- temporal attention: per (b,e,h); QKV [b,e,t] [N,768]; register softmax; O [b,e,t] [N,256] ----
__global__ __launch_bounds__(384) void k_tp_attn(const u16* __restrict__ QKV, u16* __restrict__ O) {
  __shared__ __align__(16) u16 Qs[96 * 32];
  __shared__ __align__(16) u16 Ks[96 * 32];
  __shared__ __align__(16) u16 Vs[96 * 32];
  __shared__ __align__(16) u16 Ss[96 * 96];   // P in bf16
  int blk = blockIdx.x;
  blk = (blk & 7) * ((int)gridDim.x >> 3) + (blk >> 3);  // XCD-chunked
  int h = blk & 7, e = (blk >> 3) % EE, b = blk / (8 * EE);
  long base = ((long)(b * EE + e) * TT) * 768 + h * DDm;
  int tid = threadIdx.x;
  {
    int row = tid >> 2, seg = tid & 3;
    long goff = base + (long)row * 768 + seg * 8;
    *(uint4*)&Qs[row * 32 + seg * 8] = *(const uint4*)(QKV + goff);
    *(uint4*)&Ks[row * 32 + seg * 8] = *(const uint4*)(QKV + goff + 256);
    *(uint4*)&Vs[row * 32 + seg * 8] = *(const uint4*)(QKV + goff + 512);
  }
  __syncthreads();
  int wv = tid >> 6, lane = tid & 63, lm = lane & 15, quad = lane >> 4;
  bf16x8 aq = *(const bf16x8*)&Qs[(wv * 16 + lm) * 32 + quad * 8];
  f32x4 sc[6];
#pragma unroll
  for (int j = 0; j < 6; j++) {
    bf16x8 bk = *(const bf16x8*)&Ks[(j * 16 + lm) * 32 + quad * 8];
    f32x4 z = (f32x4){0.f, 0.f, 0.f, 0.f};
    sc[j] = __builtin_amdgcn_mfma_f32_16x16x32_bf16(aq, bk, z, 0, 0, 0);
  }
  const float scale = 0.17677669529663687f;  // 1/sqrt(32)
#pragma unroll
  for (int r = 0; r < 4; r++) {
    float mx = -1e30f;
#pragma unroll
    for (int j = 0; j < 6; j++) { sc[j][r] *= scale; mx = fmaxf(mx, sc[j][r]); }
#pragma unroll
    for (int mask = 1; mask < 16; mask <<= 1) mx = fmaxf(mx, __shfl_xor(mx, mask));
    float sum = 0.f;
#pragma unroll
    for (int j = 0; j < 6; j++) { float p = __expf(sc[j][r] - mx); sc[j][r] = p; sum += p; }
#pragma unroll
    for (int mask = 1; mask < 16; mask <<= 1) sum += __shfl_xor(sum, mask);
    float inv = 1.0f / sum;
#pragma unroll
    for (int j = 0; j < 6; j++) sc[j][r] *= inv;
  }
#pragma unroll
  for (int j = 0; j < 6; j++) {
    int col = j * 16 + lm;
#pragma unroll
    for (int r = 0; r < 4; r++) Ss[(wv * 16 + quad * 4 + r) * 96 + col] = f2bf(sc[j][r]);
  }
  __syncthreads();
  f32x4 oc[2];
  oc[0] = (f32x4){0.f, 0.f, 0.f, 0.f};
  oc[1] = (f32x4){0.f, 0.f, 0.f, 0.f};
#pragma unroll
  for (int ks = 0; ks < 3; ks++) {
    bf16x8 as = *(const bf16x8*)&Ss[(wv * 16 + lm) * 96 + ks * 32 + quad * 8];
#pragma unroll
    for (int n = 0; n < 2; n++) {
      bf16x8 bv;
#pragma unroll
      for (int jj = 0; jj < 8; jj++)
        bv[jj] = (short)Vs[(ks * 32 + quad * 8 + jj) * 32 + n * 16 + lm];
      oc[n] = __builtin_amdgcn_mfma_f32_16x16x32_bf16(as, bv, oc[n], 0, 0, 0);
    }
  }
  long obase = ((long)(b * EE + e) * TT) * CC + h * DDm;
#pragma unroll
  for (int n = 0; n < 2; n++)
#pragma unroll
    for (int r = 0; r < 4; r++) {
      int row = wv * 16 + quad * 4 + r;  // t index
      O[obase + (long)row * CC + n * 16 + lm] = f2bf(oc[n][r]);
    }
}

// ------- downsample: out[b,i,e,c] = 0.5*(X[b,2i,e,c] + X[b,2i+1,e,c])  (fp32 out) -------
__global__ __launch_bounds__(256) void k_down(const float* __restrict__ X, float* __restrict__ out) {
  long i4 = ((long)blockIdx.x * 256 + threadIdx.x) * 4;
  long tmp = i4;
  int c = (int)(tmp & 255); tmp >>= 8;
  int e = (int)(tmp % EE); tmp /= EE;
  int i = (int)(tmp % TOUT);
  int b = (int)(tmp / TOUT);
  long src0 = (((long)b * TT + 2 * i) * EE + e) * CC + c;
  float4 a = *(const float4*)(X + src0);
  float4 bb = *(const float4*)(X + src0 + (long)EE * CC);
  float4 o = make_float4(0.5f * (a.x + bb.x), 0.5f * (a.y + bb.y),
                         0.5f * (a.z + bb.z), 0.5f * (a.w + bb.w));
  *(float4*)(out + i4) = o;
}

extern "C" void kernel_launch(void* const* d_in, const int* in_sizes, int n_in,
                              void* d_out, int out_size, void* d_ws, size_t ws_size,
                              hipStream_t stream) {
  (void)in_sizes; (void)n_in; (void)out_size; (void)ws_size;
  const float* x   = (const float*)d_in[0];
  const float* adj = (const float*)d_in[1];
  const float* n1g = (const float*)d_in[2];
  const float* n1b = (const float*)d_in[3];
  const float* swq = (const float*)d_in[4];
  const float* swk = (const float*)d_in[5];
  const float* swv = (const float*)d_in[6];
  const float* swp = (const float*)d_in[7];
  const float* sbp = (const float*)d_in[8];
  const float* sng = (const float*)d_in[9];
  const float* snb = (const float*)d_in[10];
  const float* sg  = (const float*)d_in[11];
  const float* n2g = (const float*)d_in[12];
  const float* n2b = (const float*)d_in[13];
  const float* twq = (const float*)d_in[14];
  const float* twk = (const float*)d_in[15];
  const float* twv = (const float*)d_in[16];
  const float* twp = (const float*)d_in[17];
  const float* tbp = (const float*)d_in[18];
  const float* tg  = (const float*)d_in[19];
  const float* n3g = (const float*)d_in[20];
  const float* n3b = (const float*)d_in[21];
  const float* mw1 = (const float*)d_in[22];
  const float* mb1 = (const float*)d_in[23];
  const float* mw2 = (const float*)d_in[24];
  const float* mb2 = (const float*)d_in[25];
  float* out = (float*)d_out;

  // ---- workspace: X fp32 | A bf16 | QKV bf16 [N,768] | weights ----
  size_t nc = (size_t)NTOK * CC;
  float* X  = (float*)d_ws;
  u16* A    = (u16*)(X + nc);
  u16* QKV  = A + nc;
  u16* Pb   = QKV;
  u16* Hh   = QKV;    // MLP: [N/2, 1024] = 75.5 MB fits in QKV (113 MB)
  u16* wts  = QKV + 3 * nc;
  u16* swq_t = wts;
  u16* swp_t = wts + 3 * 65536;
  u16* twq_t = wts + 4 * 65536;
  u16* twp_t = wts + 7 * 65536;
  u16* w1_t  = wts + 8 * 65536;  // [1024,256]
  u16* w2_t  = w1_t + 262144;    // [256,1024]
  u16* adj_b = w2_t + 262144;    // [96,96]

  WPtr8 w8; w8.p[0] = swq; w8.p[1] = swk; w8.p[2] = swv; w8.p[3] = swp;
  w8.p[4] = twq; w8.p[5] = twk; w8.p[6] = twv; w8.p[7] = twp;
  k_transpose8<<<dim3(256, 8), 256, 0, stream>>>(w8, wts);
  k_transpose<<<(256 * 1024 + 255) / 256, 256, 0, stream>>>(mw1, w1_t, 256, 1024, 256 * 1024);
  k_transpose<<<(1024 * 256 + 255) / 256, 256, 0, stream>>>(mw2, w2_t, 1024, 256, 1024 * 256);
  k_cvt<<<(EE * EE + 255) / 256, 256, 0, stream>>>(adj, adj_b, EE * EE);

  auto gemm = [&](const u16* act, const u16* Wt, const float* bias, const float* gamma,
                  u16* outB, float* Xacc, int Kd, int Nc, int lda, int ldb, int epi, int remap, int M) {
    dim3 g(Nc / 128, M / 128);
    k_gemm128<<<g, 256, 0, stream>>>(act, Wt, bias, gamma, outB, Xacc, Kd, Nc, lda, ldb, epi, remap);
  };

  int lnBlocks = NTOK / 4;

  // ---- spatial block ----
  k_ln_in<<<lnBlocks, 256, 0, stream>>>(x, A, n1g, n1b);                          // A = xs
  gemm(A, swq_t, nullptr, nullptr, QKV, nullptr, 256, 768, 256, 256, 0, 0, NTOK); // fused QKV
  k_sp_attn<<<BB * TT * HHD, 384, 0, stream>>>(QKV, adj_b, A);                    // O -> A
  gemm(A, swp_t, sbp, nullptr, Pb, nullptr, 256, 256, 256, 256, 1, 0, NTOK);      // P -> Pb
  k_sp_combine<<<lnBlocks, 256, 0, stream>>>(x, X, A, Pb, n1g, n1b, sg, sng, snb, n2g, n2b);

  // ---- temporal block (token order [b,e,t] inside) ----
  gemm(A, twq_t, nullptr, nullptr, QKV, nullptr, 256, 768, 256, 256, 0, 1, NTOK); // fused QKV, bte->bet
  k_tp_attn<<<BB * EE * HHD, 384, 0, stream>>>(QKV, A);                           // O -> A (bet)
  gemm(A, twp_t, tbp, tg, nullptr, X, 256, 256, 256, 256, 3, 2, NTOK);            // X += g*(O@wp+b), bet->bte

  // ---- MLP: token-split halves, full HID=1024 each (X RMW once per token) ----
  k_ln_f32<<<lnBlocks, 256, 0, stream>>>(X, A, n3g, n3b);                         // A = xm
  for (int hf = 0; hf < 2; hf++) {
    long r0 = (long)hf * (NTOK / 2);
    gemm(A + r0 * CC, w1_t, mb1, nullptr, Hh, nullptr, 256, 1024, 256, 256, 2, 0, NTOK / 2);
    gemm(Hh, w2_t, mb2, nullptr, nullptr, X + r0 * CC, 1024, 256, 1024, 1024, 3, 0, NTOK / 2);
  }

  // ---- downsample (fp32 out) ----
  long outElems = (long)BB * TOUT * EE * CC;
  k_down<<<(int)(outElems / 4 / 256), 256, 0, stream>>>(X, out);
}